// Round 8
// baseline (57.625 us; speedup 1.0000x reference)
//
#include <hip/hip_runtime.h>

// FractalEmbedding: cs[M,2] -> 8 Julia iters -> feats[M,16]
//                   out[M,D] = feats @ W^T * scale   (W is [D,16] row-major)
// M = 32768, D = 2048, fp32 out = 256 MiB -> write-BW-bound (fill ~7.06 TB/s).
//
// R8: R7 structure (one co-resident generation, contiguous 512 KB slab per
// block, dense 1 KB wave stores, LDS-staged cs, pk-fma dot) with DOUBLE the
// wave count: BLOCK 256->512, CPT 8->4 (W array 128->64 VGPR, total ~100)
// -> __launch_bounds__(512,4) = 4 waves/SIMD (was 2). Theory: residual 14us
// over the write floor is store-queue backpressure with too few co-resident
// waves to absorb stalls; 2x waves halves exposed stall time.

#define STEPS 8
#define KF 16
#define DDIM 2048
#define BLOCK 512
#define CPT 4                 // columns per thread: one dense 4-col group
#define ROWS_PER_BLK 64

typedef float f32x2 __attribute__((ext_vector_type(2)));
typedef float f32x4 __attribute__((ext_vector_type(4)));

__global__ __launch_bounds__(BLOCK, 4) void fractal_embed_kernel(
    const float* __restrict__ cs,     // [M,2] interleaved (cr, ci)
    const float* __restrict__ W,      // [D,16] row-major
    const float* __restrict__ scale,  // [1]
    float* __restrict__ out)          // [M,D]
{
    const int tid  = threadIdx.x;
    const int row0 = blockIdx.x * ROWS_PER_BLK;
    const int col  = tid * 4;          // cols 0..2047 across the block

    // Stage this block's 64 (cr,ci) pairs into LDS: one coalesced 512 B load.
    __shared__ float s_cs[2 * ROWS_PER_BLK];
    if (tid < 2 * ROWS_PER_BLK)
        s_cs[tid] = cs[(size_t)row0 * 2 + tid];

    const float s = scale[0];

    // W rows for this thread's 4 columns, scale folded in. 64 VGPRs.
    f32x2 w2[CPT][KF / 2];
#pragma unroll
    for (int r = 0; r < CPT; ++r) {
        const f32x2* wp = reinterpret_cast<const f32x2*>(W + (size_t)(col + r) * KF);
#pragma unroll
        for (int q = 0; q < KF / 2; ++q) {
            f32x2 v = wp[q];
            v.x *= s; v.y *= s;
            w2[r][q] = v;
        }
    }
    __syncthreads();

#pragma unroll 2
    for (int rr = 0; rr < ROWS_PER_BLK; ++rr) {
        const int row = row0 + rr;
        const float cr = s_cs[2 * rr];       // wave-uniform broadcast reads
        const float ci = s_cs[2 * rr + 1];

        // Julia iteration z <- z^2 + c from z=0; f2[st] = (zr, zi).
        f32x2 f2[STEPS];
        float zr = 0.0f, zi = 0.0f;
#pragma unroll
        for (int st = 0; st < STEPS; ++st) {
            const float nzr = fmaf(zr, zr, fmaf(-zi, zi, cr));
            const float nzi = fmaf(zr + zr, zi, ci);
            zr = nzr; zi = nzi;
            f2[st].x = zr;
            f2[st].y = zi;
        }

        // 4 dot products (length 16) via pk-fma against register W.
        f32x4 o;
#pragma unroll
        for (int r = 0; r < CPT; ++r) {
            f32x2 a2 = {0.0f, 0.0f};
#pragma unroll
            for (int q = 0; q < KF / 2; ++q)
                a2 = __builtin_elementwise_fma(f2[q], w2[r][q], a2);
            o[r] = a2.x + a2.y;
        }

        // One dense 1 KB-per-wave store; block walks a 512 KB slab row-major.
        reinterpret_cast<f32x4*>(out + (size_t)row * DDIM + col)[0] = o;
    }
}

extern "C" void kernel_launch(void* const* d_in, const int* in_sizes, int n_in,
                              void* d_out, int out_size, void* d_ws, size_t ws_size,
                              hipStream_t stream) {
    // d_in[0] = token_ids (int64, unused — cs precomputed host-side)
    // d_in[1] = cs [B,L,2] f32; d_in[2] = W [D,16] f32; d_in[3] = scale [1] f32
    const float* cs    = (const float*)d_in[1];
    const float* W     = (const float*)d_in[2];
    const float* scale = (const float*)d_in[3];
    float* out         = (float*)d_out;

    const int M = in_sizes[0];                 // B*L = 32768 rows
    const int grid = M / ROWS_PER_BLK;         // 512 blocks: one generation
    fractal_embed_kernel<<<grid, BLOCK, 0, stream>>>(cs, W, scale, out);
}

// Round 9
// 52.065 us; speedup vs baseline: 1.1068x; 1.1068x over previous
//
#include <hip/hip_runtime.h>

// FractalEmbedding: cs[M,2] -> 8 Julia iters -> feats[M,16]
//                   out[M,D] = feats @ W^T * scale   (W is [D,16] row-major)
// M = 32768, D = 2048, fp32 out = 256 MiB -> write-BW-bound (fill ~7.06 TB/s).
//
// R9: R7 structure exactly (one co-resident generation: 512 blocks x 256 thr,
// contiguous 512 KB slab per block, dense 1 KB wave stores, LDS-staged cs,
// pk-fma dot, launch_bounds(256,2)) with the row loop unroll 2 -> 4.
// Theory: fill never waits on its stores (constant data reg); we must wait
// vmcnt before reusing accumulator regs. Unroll 4 doubles in-flight stores
// per wave (~4 -> ~8), pushing the s_waitcnt vmcnt reuse-wait 4 iterations
// back and doubling per-CU outstanding store bytes (the R7/R8 invariant).

#define STEPS 8
#define KF 16
#define DDIM 2048
#define BLOCK 256
#define CPT 8                 // columns per thread: two dense 4-col groups
#define ROWS_PER_BLK 64

typedef float f32x2 __attribute__((ext_vector_type(2)));
typedef float f32x4 __attribute__((ext_vector_type(4)));

__global__ __launch_bounds__(BLOCK, 2) void fractal_embed_kernel(
    const float* __restrict__ cs,     // [M,2] interleaved (cr, ci)
    const float* __restrict__ W,      // [D,16] row-major
    const float* __restrict__ scale,  // [1]
    float* __restrict__ out)          // [M,D]
{
    const int tid  = threadIdx.x;
    const int row0 = blockIdx.x * ROWS_PER_BLK;
    const int ca   = tid * 4;          // cols    0..1023 across the block
    const int cb   = 1024 + tid * 4;   // cols 1024..2047 across the block

    // Stage this block's 64 (cr,ci) pairs into LDS: one coalesced 512 B load.
    __shared__ float s_cs[2 * ROWS_PER_BLK];
    if (tid < 2 * ROWS_PER_BLK)
        s_cs[tid] = cs[(size_t)row0 * 2 + tid];

    const float s = scale[0];

    // W rows for this thread's 8 columns, scale folded in. 128 VGPRs.
    f32x2 w2[CPT][KF / 2];
#pragma unroll
    for (int r = 0; r < CPT; ++r) {
        const int d = (r < 4) ? (ca + r) : (cb + (r - 4));
        const f32x2* wp = reinterpret_cast<const f32x2*>(W + (size_t)d * KF);
#pragma unroll
        for (int q = 0; q < KF / 2; ++q) {
            f32x2 v = wp[q];
            v.x *= s; v.y *= s;
            w2[r][q] = v;
        }
    }
    __syncthreads();

#pragma unroll 4
    for (int rr = 0; rr < ROWS_PER_BLK; ++rr) {
        const int row = row0 + rr;
        const float cr = s_cs[2 * rr];       // wave-uniform broadcast reads
        const float ci = s_cs[2 * rr + 1];

        // Julia iteration z <- z^2 + c from z=0; f2[st] = (zr, zi).
        f32x2 f2[STEPS];
        float zr = 0.0f, zi = 0.0f;
#pragma unroll
        for (int st = 0; st < STEPS; ++st) {
            const float nzr = fmaf(zr, zr, fmaf(-zi, zi, cr));
            const float nzi = fmaf(zr + zr, zi, ci);
            zr = nzr; zi = nzi;
            f2[st].x = zr;
            f2[st].y = zi;
        }

        // 8 dot products (length 16) via pk-fma against register W.
        f32x4 oa, ob;
#pragma unroll
        for (int r = 0; r < CPT; ++r) {
            f32x2 a2 = {0.0f, 0.0f};
#pragma unroll
            for (int q = 0; q < KF / 2; ++q)
                a2 = __builtin_elementwise_fma(f2[q], w2[r][q], a2);
            const float v = a2.x + a2.y;
            if (r < 4) oa[r] = v;
            else       ob[r - 4] = v;
        }

        // Two dense 1 KB-per-wave stores; block walks a 512 KB slab row-major.
        float* rowp = out + (size_t)row * DDIM;
        reinterpret_cast<f32x4*>(rowp + ca)[0] = oa;
        reinterpret_cast<f32x4*>(rowp + cb)[0] = ob;
    }
}

extern "C" void kernel_launch(void* const* d_in, const int* in_sizes, int n_in,
                              void* d_out, int out_size, void* d_ws, size_t ws_size,
                              hipStream_t stream) {
    // d_in[0] = token_ids (int64, unused — cs precomputed host-side)
    // d_in[1] = cs [B,L,2] f32; d_in[2] = W [D,16] f32; d_in[3] = scale [1] f32
    const float* cs    = (const float*)d_in[1];
    const float* W     = (const float*)d_in[2];
    const float* scale = (const float*)d_in[3];
    float* out         = (float*)d_out;

    const int M = in_sizes[0];                 // B*L = 32768 rows
    const int grid = M / ROWS_PER_BLK;         // 512 blocks: one generation
    fractal_embed_kernel<<<grid, BLOCK, 0, stream>>>(cs, W, scale, out);
}